// Round 2
// baseline (113.814 us; speedup 1.0000x reference)
//
#include <hip/hip_runtime.h>

#define NROWS 2048
#define MLEN  3000
#define LPAD  4096
#define PAD0  548
#define NLVL  8
#define NT    256

// LDS budget: SA 16KB + SB 8KB + filters 0.5KB = 24.5KB -> 6 blocks/CU (75% occ ceiling).
// Analysis approx levels stored polyphase-split ([evens|odds]) -> lane-stride-1 LDS reads,
// conflict-free. Details are written straight to global (they ARE the coeffs output) and
// read back from L2 during synthesis.
__global__ __launch_bounds__(NT) void despawn_kernel(
    const float* __restrict__ x,
    const float* __restrict__ scaling,
    const float* __restrict__ scaling_rec,
    float* __restrict__ recon_out,
    float* __restrict__ coef_out)
{
    __shared__ float SA[LPAD];        // 16 KB
    __shared__ float SB[LPAD / 2];    // 8 KB
    __shared__ float fsca[NLVL * 8];
    __shared__ float fwav[NLVL * 8];

    const int tid = threadIdx.x;
    const int row = blockIdx.x;
    float* const crow = coef_out + (size_t)row * LPAD;

    // wav[k] = scaling_rec[lvl][7-k] * (-1)^k   (_make_wavelet: flip + alternate signs)
    if (tid < NLVL * 8) {
        const int lvl = tid >> 3, k = tid & 7;
        fsca[tid] = scaling[tid];
        fwav[tid] = scaling_rec[lvl * 8 + (7 - k)] * ((k & 1) ? -1.0f : 1.0f);
    }

    // Load row with edge padding, into SA in split (polyphase) layout:
    // natural index i -> (i even) SA[i/2] ; (i odd) SA[2048 + i/2]
    const float* xr = x + (size_t)row * MLEN;
    for (int i = tid; i < LPAD; i += NT) {
        int j = i - PAD0;
        j = j < 0 ? 0 : (j > MLEN - 1 ? MLEN - 1 : j);
        SA[((i & 1) ? (LPAD / 2) : 0) + (i >> 1)] = xr[j];
    }
    __syncthreads();

    // ---------------- analysis ----------------
    // out[j] = sum_k in[(2j-k) mod M] f[k]
    //        = sum_m ev[(j-m) mod M/2] f[2m] + od[(j-m-1) mod M/2] f[2m+1]
    float* cur = SA;
    float* alt = SB;
    int M = LPAD;
    int coff = 0;
    for (int lvl = 0; lvl < NLVL; ++lvl) {
        const int H = M >> 1;           // number of outputs == input half-length
        const int hm = H - 1;
        const float* we = &fwav[lvl * 8];
        const float* se = &fsca[lvl * 8];
        const float* ev = cur;
        const float* od = cur + H;
        for (int j = tid; j < H; j += NT) {
            float ds = 0.0f, as = 0.0f;
#pragma unroll
            for (int m = 0; m < 4; ++m) {
                const float vE = ev[(j - m) & hm];
                const float vO = od[(j - m - 1) & hm];
                ds = fmaf(vE, we[2 * m], ds);
                ds = fmaf(vO, we[2 * m + 1], ds);
                as = fmaf(vE, se[2 * m], as);
                as = fmaf(vO, se[2 * m + 1], as);
            }
            crow[coff + j] = ds;                                   // write-through details
            alt[((j & 1) ? (H >> 1) : 0) + (j >> 1)] = as;         // split layout for next lvl
        }
        __syncthreads();
        coff += H;
        float* t = cur; cur = alt; alt = t;
        M = H;
    }
    // Final approx: length 16, split in `cur` (== SA after 8 swaps).
    // Emit natural order to global (coeffs tail) and to SA[16..32) for synthesis start.
    if (tid < 16) {
        const float v = cur[((tid & 1) ? 8 : 0) + (tid >> 1)];
        crow[LPAD - 16 + tid] = v;
        SA[16 + tid] = v;
    }
    __syncthreads();

    // ---------------- synthesis ----------------
    // out[n] = sum_{k ≡ n (mod 2)} d[((n+k)/2) mod len]*wav[k] + a[((n+k)/2) mod len]*sca[k]
    // d comes from global (L2-resident, just written); a ping-pongs in LDS (natural order).
    const float* a = SA + 16;
    int len = 16;
    float* obuf = SB;   // 32->SB,64->SA,128->SB,256->SA,512->SB,1024->SA,2048->SB,4096->SA
    for (int lvl = NLVL - 1; lvl >= 0; --lvl) {
        const int Mout = len << 1;
        const int lmask = len - 1;
        const float* d = crow + (LPAD - (LPAD >> lvl));
        const float* we = &fwav[lvl * 8];
        const float* se = &fsca[lvl * 8];
        for (int n = tid; n < Mout; n += NT) {
            const int p = n & 1;
            const int i0 = (n + p) >> 1;
            float sum = 0.0f;
#pragma unroll
            for (int m = 0; m < 4; ++m) {
                const int idx = (i0 + m) & lmask;
                sum = fmaf(d[idx], we[p + 2 * m], sum);
                sum = fmaf(a[idx], se[p + 2 * m], sum);
            }
            obuf[n] = sum;
        }
        __syncthreads();
        a = obuf;
        len = Mout;
        obuf = (obuf == SB) ? SA : SB;
    }
    // a == SA, length 4096 natural-order reconstruction

    float* ro = recon_out + (size_t)row * MLEN;
    for (int i = tid; i < MLEN; i += NT) ro[i] = a[PAD0 + i];
}

extern "C" void kernel_launch(void* const* d_in, const int* in_sizes, int n_in,
                              void* d_out, int out_size, void* d_ws, size_t ws_size,
                              hipStream_t stream) {
    const float* x           = (const float*)d_in[0];
    const float* scaling     = (const float*)d_in[1];
    const float* scaling_rec = (const float*)d_in[2];
    float* recon = (float*)d_out;                       // 2048*3000 floats
    float* coefo = recon + (size_t)NROWS * MLEN;        // 2048*4096 floats
    despawn_kernel<<<dim3(NROWS), dim3(NT), 0, stream>>>(x, scaling, scaling_rec,
                                                         recon, coefo);
    (void)in_sizes; (void)n_in; (void)out_size; (void)d_ws; (void)ws_size;
}

// Round 3
// 99.577 us; speedup vs baseline: 1.1430x; 1.1430x over previous
//
#include <hip/hip_runtime.h>

#define NROWS 2048
#define MLEN  3000
#define LPAD  4096
#define PAD0  548
#define NLVL  8
#define NT    256

union F4 { float4 v; float f[4]; };

// LDS: SA 16KB + SB 8KB + CS 2KB + filters 0.5KB = 26.5KB -> 6 blocks/CU.
// All LDS traffic is b128/b64 (8x fewer LDS instrs than scalar version: LDS pipe
// was the R1/R2 bottleneck at ~39us of ds_read_b32 throughput).
// CS mirrors crow[3584..4096) (details lvl>=3 + final approx) so thin synthesis
// levels never touch global; wide levels (0-2) re-read details from L2.
__global__ __launch_bounds__(NT) void despawn_kernel(
    const float* __restrict__ x,
    const float* __restrict__ scaling,
    const float* __restrict__ scaling_rec,
    float* __restrict__ recon_out,
    float* __restrict__ coef_out)
{
    __shared__ __align__(16) float SA[LPAD];      // 16 KB
    __shared__ __align__(16) float SB[LPAD / 2];  // 8 KB
    __shared__ __align__(16) float CS[512];       // 2 KB
    __shared__ float fsca[64];
    __shared__ float fwav[64];

    const int tid = threadIdx.x;
    const int row = blockIdx.x;
    float* const crow = coef_out + (size_t)row * LPAD;

    // wav[k] = scaling_rec[lvl][7-k] * (-1)^k  (_make_wavelet)
    if (tid < 64) {
        const int lvl = tid >> 3, k = tid & 7;
        fsca[tid] = scaling[tid];
        fwav[tid] = scaling_rec[lvl * 8 + (7 - k)] * ((k & 1) ? -1.0f : 1.0f);
    }

    // ---- stage input (edge-padded) into SA, polyphase split [evens|odds] ----
    const float* xr = x + (size_t)row * MLEN;
    const float xlo = xr[0], xhi = xr[MLEN - 1];
    {
        const float4* xr4 = reinterpret_cast<const float4*>(xr);
        for (int g = tid; g < MLEN / 4; g += NT) {
            F4 u; u.v = xr4[g];
            const int h = PAD0 / 2 + 2 * g;    // natural index PAD0+4g, even half pos
            *reinterpret_cast<float2*>(&SA[h])            = make_float2(u.f[0], u.f[2]);
            *reinterpret_cast<float2*>(&SA[LPAD / 2 + h]) = make_float2(u.f[1], u.f[3]);
        }
    }
    for (int i = tid; i < PAD0 / 2; i += NT) {   // 274 positions per edge per parity
        SA[i] = xlo;
        SA[LPAD / 2 + i] = xlo;
        SA[PAD0 / 2 + MLEN / 2 + i] = xhi;                  // 1774 + i
        SA[LPAD / 2 + PAD0 / 2 + MLEN / 2 + i] = xhi;
    }
    __syncthreads();

    // ---------------- analysis ----------------
    // out[j] = sum_m ev[(j-m)&hm]*f[2m] + od[(j-m-1)&hm]*f[2m+1]
    {
        float* cur = SA;
        float* alt = SB;
        int H = LPAD / 2;
        int coff = 0;
        for (int lvl = 0; lvl < NLVL; ++lvl) {
            float W[8], S[8];
#pragma unroll
            for (int k = 0; k < 8; ++k) { W[k] = fwav[lvl * 8 + k]; S[k] = fsca[lvl * 8 + k]; }
            const int q = H >> 2;        // one thread = 4 consecutive outputs
            const int qm = q - 1;
            const float4* ev4 = reinterpret_cast<const float4*>(cur);
            const float4* od4 = reinterpret_cast<const float4*>(cur + H);
            float4* dst4 = reinterpret_cast<float4*>(crow + coff);
            float4* cs4 = (lvl >= 3) ? reinterpret_cast<float4*>(&CS[coff - 3584]) : nullptr;
            for (int t = tid; t < q; t += NT) {
                F4 Ea, Eb, Oa, Ob;
                Ea.v = ev4[(t - 1) & qm];  // ev[j0-4 .. j0-1]
                Eb.v = ev4[t];             // ev[j0   .. j0+3]
                Oa.v = od4[(t - 1) & qm];
                Ob.v = od4[t];
                float e[8] = {Ea.f[0],Ea.f[1],Ea.f[2],Ea.f[3],Eb.f[0],Eb.f[1],Eb.f[2],Eb.f[3]};
                float o[8] = {Oa.f[0],Oa.f[1],Oa.f[2],Oa.f[3],Ob.f[0],Ob.f[1],Ob.f[2],Ob.f[3]};
                float ds[4], as[4];
#pragma unroll
                for (int u = 0; u < 4; ++u) {
                    float d = 0.f, a = 0.f;
#pragma unroll
                    for (int m = 0; m < 4; ++m) {
                        const float vE = e[4 + u - m];   // ev[j0+u-m]
                        const float vO = o[3 + u - m];   // od[j0+u-m-1]
                        d = fmaf(vE, W[2 * m], d);
                        d = fmaf(vO, W[2 * m + 1], d);
                        a = fmaf(vE, S[2 * m], a);
                        a = fmaf(vO, S[2 * m + 1], a);
                    }
                    ds[u] = d; as[u] = a;
                }
                F4 dv; dv.f[0] = ds[0]; dv.f[1] = ds[1]; dv.f[2] = ds[2]; dv.f[3] = ds[3];
                dst4[t] = dv.v;                    // details -> global (coeffs output)
                if (cs4) cs4[t] = dv.v;            // thin levels also -> LDS mirror
                // approx -> split layout for next level
                *reinterpret_cast<float2*>(alt + 2 * t)            = make_float2(as[0], as[2]);
                *reinterpret_cast<float2*>(alt + (H >> 1) + 2 * t) = make_float2(as[1], as[3]);
            }
            __syncthreads();
            coff += H;
            float* tmp = cur; cur = alt; alt = tmp;
            H >>= 1;
        }
    }

    // final approx (split, 16, in SA) -> natural order in crow tail + CS tail
    if (tid < 16) {
        const float v = SA[((tid & 1) ? 8 : 0) + (tid >> 1)];
        crow[LPAD - 16 + tid] = v;
        CS[496 + tid] = v;
    }
    __syncthreads();

    // ---------------- synthesis ----------------
    // out[n] = sum_{k≡n mod 2} d[((n+p)/2+m)&lm]*wav[k] + a[..]*sca[k], k=p+2m
    const float* a = &CS[496];
    float* obuf = SB;
    int len = 16;
    for (int lvl = NLVL - 1; lvl >= 1; --lvl) {
        float W[8], S[8];
#pragma unroll
        for (int k = 0; k < 8; ++k) { W[k] = fwav[lvl * 8 + k]; S[k] = fsca[lvl * 8 + k]; }
        const int Mout = len << 1;
        const int doff = LPAD - (LPAD >> lvl);
        const float4* d4 = (lvl >= 3)
            ? reinterpret_cast<const float4*>(&CS[doff - 3584])
            : reinterpret_cast<const float4*>(crow + doff);
        const float4* a4 = reinterpret_cast<const float4*>(a);
        const int gq = Mout >> 3;      // one thread = 8 consecutive outputs
        const int fm = (len >> 2) - 1;
        for (int g = tid; g < gq; g += NT) {
            F4 Da, Db, Aa, Ab;
            Da.v = d4[g]; Db.v = d4[(g + 1) & fm];   // d[4g .. 4g+7] circular
            Aa.v = a4[g]; Ab.v = a4[(g + 1) & fm];
            float dd[8] = {Da.f[0],Da.f[1],Da.f[2],Da.f[3],Db.f[0],Db.f[1],Db.f[2],Db.f[3]};
            float aa[8] = {Aa.f[0],Aa.f[1],Aa.f[2],Aa.f[3],Ab.f[0],Ab.f[1],Ab.f[2],Ab.f[3]};
            float out[8];
#pragma unroll
            for (int u = 0; u < 8; ++u) {
                const int p = u & 1, c = (u + 1) >> 1;
                float s = 0.f;
#pragma unroll
                for (int m = 0; m < 4; ++m) {
                    s = fmaf(dd[c + m], W[p + 2 * m], s);
                    s = fmaf(aa[c + m], S[p + 2 * m], s);
                }
                out[u] = s;
            }
            F4 o0, o1;
            o0.f[0] = out[0]; o0.f[1] = out[1]; o0.f[2] = out[2]; o0.f[3] = out[3];
            o1.f[0] = out[4]; o1.f[1] = out[5]; o1.f[2] = out[6]; o1.f[3] = out[7];
            float4* ob4 = reinterpret_cast<float4*>(obuf + 8 * g);
            ob4[0] = o0.v; ob4[1] = o1.v;
        }
        __syncthreads();
        a = obuf;
        obuf = (obuf == SB) ? SA : SB;
        len = Mout;
    }
    // lvl 0: write reconstruction straight to global (no LDS round-trip)
    {
        float W[8], S[8];
#pragma unroll
        for (int k = 0; k < 8; ++k) { W[k] = fwav[k]; S[k] = fsca[k]; }
        const float4* d4 = reinterpret_cast<const float4*>(crow);   // lvl0 details at offset 0
        const float4* a4 = reinterpret_cast<const float4*>(a);      // SB, 2048 approx
        const int fm = (len >> 2) - 1;                              // len == 2048
        float* const ro = recon_out + (size_t)row * MLEN;
        for (int g = tid; g < (LPAD >> 3); g += NT) {
            F4 Da, Db, Aa, Ab;
            Da.v = d4[g]; Db.v = d4[(g + 1) & fm];
            Aa.v = a4[g]; Ab.v = a4[(g + 1) & fm];
            float dd[8] = {Da.f[0],Da.f[1],Da.f[2],Da.f[3],Db.f[0],Db.f[1],Db.f[2],Db.f[3]};
            float aa[8] = {Aa.f[0],Aa.f[1],Aa.f[2],Aa.f[3],Ab.f[0],Ab.f[1],Ab.f[2],Ab.f[3]};
            float out[8];
#pragma unroll
            for (int u = 0; u < 8; ++u) {
                const int p = u & 1, c = (u + 1) >> 1;
                float s = 0.f;
#pragma unroll
                for (int m = 0; m < 4; ++m) {
                    s = fmaf(dd[c + m], W[p + 2 * m], s);
                    s = fmaf(aa[c + m], S[p + 2 * m], s);
                }
                out[u] = s;
            }
            const int n0 = 8 * g;
            if (n0 >= PAD0 && n0 + 8 <= PAD0 + MLEN) {
                F4 o0, o1;
                o0.f[0] = out[0]; o0.f[1] = out[1]; o0.f[2] = out[2]; o0.f[3] = out[3];
                o1.f[0] = out[4]; o1.f[1] = out[5]; o1.f[2] = out[6]; o1.f[3] = out[7];
                float4* r4 = reinterpret_cast<float4*>(ro + (n0 - PAD0));
                r4[0] = o0.v; r4[1] = o1.v;
            } else {
#pragma unroll
                for (int u = 0; u < 8; ++u) {
                    const int n = n0 + u;
                    if (n >= PAD0 && n < PAD0 + MLEN) ro[n - PAD0] = out[u];
                }
            }
        }
    }
}

extern "C" void kernel_launch(void* const* d_in, const int* in_sizes, int n_in,
                              void* d_out, int out_size, void* d_ws, size_t ws_size,
                              hipStream_t stream) {
    const float* x           = (const float*)d_in[0];
    const float* scaling     = (const float*)d_in[1];
    const float* scaling_rec = (const float*)d_in[2];
    float* recon = (float*)d_out;                       // 2048*3000 floats
    float* coefo = recon + (size_t)NROWS * MLEN;        // 2048*4096 floats
    despawn_kernel<<<dim3(NROWS), dim3(NT), 0, stream>>>(x, scaling, scaling_rec,
                                                         recon, coefo);
    (void)in_sizes; (void)n_in; (void)out_size; (void)d_ws; (void)ws_size;
}